// Round 1
// baseline (246.285 us; speedup 1.0000x reference)
//
#include <hip/hip_runtime.h>
#include <math.h>

#define B_ 64
#define L_ 64
#define D_ 300
#define H_ 128
#define C_ 50
#define NC_ 2
#define TWO_D 600
#define M_ (B_*L_)      // 4096
#define Q_ 600          // 150 + 200 + 250 conv weight columns

// ---------------- gather: fv[m][0:300] = embedmatrix[x[m]] ----------------
__global__ void k_gather(const int* __restrict__ x, const float* __restrict__ em,
                         float* __restrict__ fv) {
    int m = blockIdx.x;
    int row = x[m];
    const float* src = em + (size_t)row * D_;
    float* dst = fv + (size_t)m * TWO_D;
    for (int d = threadIdx.x; d < D_; d += blockDim.x) dst[d] = src[d];
}

// ---------------- build Wt[d][q]: transposed conv weights ----------------
// q in [0,150): conv1 (ks=3)  c=q/3  i=q%3
// q in [150,350): conv2 (ks=4) c=(q-150)/4 i=(q-150)%4
// q in [350,600): conv3 (ks=5) c=(q-350)/5 i=(q-350)%5
__global__ void k_wt(const float* __restrict__ w1, const float* __restrict__ w2,
                     const float* __restrict__ w3, float* __restrict__ wt) {
    int idx = blockIdx.x * blockDim.x + threadIdx.x;
    if (idx >= TWO_D * Q_) return;
    int d = idx / Q_, q = idx % Q_;
    float v;
    if (q < 150)      { int c = q/3,       i = q%3;       v = w1[((size_t)c*TWO_D + d)*3 + i]; }
    else if (q < 350) { int r = q-150; int c = r/4, i = r%4; v = w2[((size_t)c*TWO_D + d)*4 + i]; }
    else              { int r = q-350; int c = r/5, i = r%5; v = w3[((size_t)c*TWO_D + d)*5 + i]; }
    wt[idx] = v;   // wt[d*600 + q]
}

// ---------------- pa = emb@w1a + b1 ; pb = emb@w1b ----------------
__global__ void k_papb(const float* __restrict__ fv,
                       const float* __restrict__ w1a, const float* __restrict__ w1b,
                       const float* __restrict__ b1,
                       float* __restrict__ pa, float* __restrict__ pb) {
    int m = blockIdx.x;
    __shared__ float s_emb[D_];
    for (int d = threadIdx.x; d < D_; d += blockDim.x)
        s_emb[d] = fv[(size_t)m * TWO_D + d];
    __syncthreads();
    int h = threadIdx.x;   // 128 threads
    float acc_a = b1[h];
    float acc_b = 0.f;
    for (int d = 0; d < D_; ++d) {
        float e = s_emb[d];
        acc_a += e * w1a[(size_t)d * H_ + h];
        acc_b += e * w1b[(size_t)d * H_ + h];
    }
    pa[(size_t)m * H_ + h] = acc_a;
    pb[(size_t)m * H_ + h] = acc_b;
}

// ---------------- attention: one block per (b,i) ----------------
__global__ void k_attn(const float* __restrict__ pa, const float* __restrict__ pb,
                       const float* __restrict__ w2, const float* __restrict__ b2,
                       float* __restrict__ fv) {
    int m = blockIdx.x;
    int b = m >> 6, i = m & 63;
    __shared__ float s_pa[H_], s_w2[H_], s_sc[64];
    int tid = threadIdx.x;   // 256 threads = 4 waves
    if (tid < H_) { s_pa[tid] = pa[(size_t)m * H_ + tid]; s_w2[tid] = w2[tid]; }
    __syncthreads();
    int wave = tid >> 6, lane = tid & 63;
    float pa0 = s_pa[lane], pa1 = s_pa[lane + 64];
    float w20 = s_w2[lane], w21 = s_w2[lane + 64];
    float b2v = b2[0];
    for (int k = wave; k < L_ - 1; k += 4) {
        const float* pbr = pb + (size_t)(b * L_ + k) * H_;
        float p = w20 * tanhf(pa0 + pbr[lane]) + w21 * tanhf(pa1 + pbr[lane + 64]);
        #pragma unroll
        for (int off = 32; off; off >>= 1) p += __shfl_xor(p, off, 64);
        if (lane == 0) s_sc[k] = p + b2v;
    }
    __syncthreads();
    if (tid < 64) {
        // softmax over 63 values with decay, single wave
        float v = -INFINITY;
        if (tid < L_ - 1) {
            float e = fabsf((float)(i - tid)) - 1.0f;   // compacted index for decay
            v = powf(0.9f, e) * s_sc[tid];
        }
        float mx = v;
        #pragma unroll
        for (int off = 32; off; off >>= 1) mx = fmaxf(mx, __shfl_xor(mx, off, 64));
        float ex = (tid < L_ - 1) ? expf(v - mx) : 0.f;
        float sm = ex;
        #pragma unroll
        for (int off = 32; off; off >>= 1) sm += __shfl_xor(sm, off, 64);
        if (tid < L_ - 1) s_sc[tid] = ex / sm;
    }
    __syncthreads();
    // att[b,i,d] = sum_k alpha[k] * emb[b, k + (k>=i), d]  -> fv[m][300+d]
    for (int d = tid; d < D_; d += blockDim.x) {
        float acc = 0.f;
        for (int k = 0; k < L_ - 1; ++k) {
            int j = k + (k >= i);
            acc += s_sc[k] * fv[(size_t)(b * L_ + j) * TWO_D + d];
        }
        fv[(size_t)m * TWO_D + D_ + d] = acc;
    }
}

// ---------------- GEMM: G[4096][600] = fv[4096][600] @ Wt[600][600] ----------------
#define TM 64
#define TN 64
#define TK 16
__global__ __launch_bounds__(256) void k_gemm(const float* __restrict__ A,
                                              const float* __restrict__ Bw,
                                              float* __restrict__ G) {
    __shared__ float As[TK][TM];
    __shared__ float Bs[TK][TN + 1];
    int m0 = blockIdx.x * TM;
    int q0 = blockIdx.y * TN;
    int tid = threadIdx.x;
    int tx = tid & 15, ty = tid >> 4;
    float acc[4][4] = {};
    for (int k0 = 0; k0 < TWO_D; k0 += TK) {
        #pragma unroll
        for (int e = 0; e < 4; ++e) {
            int le = tid * 4 + e;           // 0..1023
            int mm = le >> 4, kk = le & 15;
            float v = 0.f;
            if (k0 + kk < TWO_D) v = A[(size_t)(m0 + mm) * TWO_D + k0 + kk];
            As[kk][mm] = v;
        }
        #pragma unroll
        for (int e = 0; e < 4; ++e) {
            int le = tid * 4 + e;
            int kk = le >> 6, nn = le & 63;
            float v = 0.f;
            if (k0 + kk < TWO_D && q0 + nn < Q_) v = Bw[(size_t)(k0 + kk) * Q_ + q0 + nn];
            Bs[kk][nn] = v;
        }
        __syncthreads();
        #pragma unroll
        for (int k = 0; k < TK; ++k) {
            float a[4], bb[4];
            #pragma unroll
            for (int u = 0; u < 4; ++u) a[u] = As[k][ty * 4 + u];
            #pragma unroll
            for (int u = 0; u < 4; ++u) bb[u] = Bs[k][tx * 4 + u];
            #pragma unroll
            for (int u = 0; u < 4; ++u)
                #pragma unroll
                for (int v = 0; v < 4; ++v) acc[u][v] += a[u] * bb[v];
        }
        __syncthreads();
    }
    #pragma unroll
    for (int u = 0; u < 4; ++u) {
        int mm = m0 + ty * 4 + u;
        #pragma unroll
        for (int v = 0; v < 4; ++v) {
            int nn = q0 + tx * 4 + v;
            if (nn < Q_) G[(size_t)mm * Q_ + nn] = acc[u][v];
        }
    }
}

// ---------------- conv bias + maxpool over valid t ----------------
__global__ void k_pool(const float* __restrict__ G, const float* __restrict__ cb1,
                       const float* __restrict__ cb2, const float* __restrict__ cb3,
                       float* __restrict__ conout) {
    int blk = blockIdx.x;     // b*150 + p
    int b = blk / 150, p = blk % 150;
    int ks, qb; float bias;
    if (p < 50)       { ks = 3; qb = p * 3;            bias = cb1[p]; }
    else if (p < 100) { int c = p - 50;  ks = 4; qb = 150 + c * 4; bias = cb2[c]; }
    else              { int c = p - 100; ks = 5; qb = 350 + c * 5; bias = cb3[c]; }
    int T = L_ - ks + 1;
    int t = threadIdx.x;      // 64 threads = 1 wave
    float y = -INFINITY;
    if (t < T) {
        float s = bias;
        for (int i = 0; i < ks; ++i)
            s += G[(size_t)(b * L_ + t + i) * Q_ + qb + i];
        y = s;
    }
    #pragma unroll
    for (int off = 32; off; off >>= 1) y = fmaxf(y, __shfl_xor(y, off, 64));
    if (t == 0) conout[b * 150 + p] = y;
}

// ---------------- final linear + log_softmax ----------------
__global__ void k_final(const float* __restrict__ conout, const float* __restrict__ lw,
                        const float* __restrict__ lb, float* __restrict__ out) {
    int b = threadIdx.x;      // 64 threads, 1 block
    if (b >= B_) return;
    float l0 = lb[0], l1 = lb[1];
    const float* co = conout + b * 150;
    for (int m = 0; m < 150; ++m) {
        float v = co[m];
        l0 += v * lw[m * 2 + 0];
        l1 += v * lw[m * 2 + 1];
    }
    float mx = fmaxf(l0, l1);
    float ls = mx + logf(expf(l0 - mx) + expf(l1 - mx));
    out[b * 2 + 0] = l0 - ls;
    out[b * 2 + 1] = l1 - ls;
}

extern "C" void kernel_launch(void* const* d_in, const int* in_sizes, int n_in,
                              void* d_out, int out_size, void* d_ws, size_t ws_size,
                              hipStream_t stream) {
    const int*   x   = (const int*)  d_in[0];
    const float* em  = (const float*)d_in[1];
    const float* w1a = (const float*)d_in[2];
    const float* w1b = (const float*)d_in[3];
    const float* b1  = (const float*)d_in[4];
    const float* w2  = (const float*)d_in[5];
    const float* b2  = (const float*)d_in[6];
    const float* cw1 = (const float*)d_in[7];
    const float* cb1 = (const float*)d_in[8];
    const float* cw2 = (const float*)d_in[9];
    const float* cb2 = (const float*)d_in[10];
    const float* cw3 = (const float*)d_in[11];
    const float* cb3 = (const float*)d_in[12];
    const float* lw  = (const float*)d_in[13];
    const float* lb  = (const float*)d_in[14];
    float* out = (float*)d_out;

    float* ws = (float*)d_ws;
    float* fv     = ws;                 // [4096][600]  emb | att   (2,457,600 f)
    float* G      = ws + 2457600;       // [4096][600]             (2,457,600 f)
    float* pa     = ws + 4915200;       // [4096][128]             (  524,288 f)
    float* pb     = ws + 5439488;       // [4096][128]             (  524,288 f)
    float* Wt     = ws + 5963776;       // [600][600]              (  360,000 f)
    float* conout = ws + 6323776;       // [64][150]               (    9,600 f)
    // total ~25.3 MB of workspace

    hipLaunchKernelGGL(k_gather, dim3(M_), dim3(256), 0, stream, x, em, fv);
    hipLaunchKernelGGL(k_wt, dim3((TWO_D * Q_ + 255) / 256), dim3(256), 0, stream,
                       cw1, cw2, cw3, Wt);
    hipLaunchKernelGGL(k_papb, dim3(M_), dim3(128), 0, stream, fv, w1a, w1b, b1, pa, pb);
    hipLaunchKernelGGL(k_attn, dim3(M_), dim3(256), 0, stream, pa, pb, w2, b2, fv);
    hipLaunchKernelGGL(k_gemm, dim3(M_ / TM, (Q_ + TN - 1) / TN), dim3(256), 0, stream,
                       fv, Wt, G);
    hipLaunchKernelGGL(k_pool, dim3(B_ * 150), dim3(64), 0, stream, G, cb1, cb2, cb3, conout);
    hipLaunchKernelGGL(k_final, dim3(1), dim3(64), 0, stream, conout, lw, lb, out);
}

// Round 2
// 171.492 us; speedup vs baseline: 1.4361x; 1.4361x over previous
//
#include <hip/hip_runtime.h>
#include <math.h>

#define B_ 64
#define L_ 64
#define D_ 300
#define H_ 128
#define C_ 50
#define NC_ 2
#define TWO_D 600
#define M_ (B_*L_)      // 4096
#define Q_ 600          // logical conv columns
#define QP 640          // padded N
#define KP 608          // padded K (19*32)

typedef short short8 __attribute__((ext_vector_type(8)));
typedef float floatx4 __attribute__((ext_vector_type(4)));

static __device__ __forceinline__ unsigned short f2bf(float f) {
    unsigned int u = __float_as_uint(f);
    u += 0x7FFFu + ((u >> 16) & 1u);   // round-to-nearest-even
    return (unsigned short)(u >> 16);
}

// ---------------- gather: fv[m][0:300] = embedmatrix[x[m]] ----------------
__global__ void k_gather(const int* __restrict__ x, const float* __restrict__ em,
                         float* __restrict__ fv) {
    int m = blockIdx.x;
    int row = x[m];
    const float* src = em + (size_t)row * D_;
    float* dst = fv + (size_t)m * TWO_D;
    for (int d = threadIdx.x; d < D_; d += blockDim.x) dst[d] = src[d];
}

// ---------------- build WtT[q][d] (bf16, padded to [640][608]) ----------------
__global__ void k_wtT(const float* __restrict__ w1, const float* __restrict__ w2,
                      const float* __restrict__ w3, unsigned short* __restrict__ wtT) {
    int idx = blockIdx.x * blockDim.x + threadIdx.x;
    if (idx >= QP * KP) return;
    int q = idx / KP, d = idx % KP;
    float v = 0.f;
    if (q < Q_ && d < TWO_D) {
        if (q < 150)      { int c = q/3,           i = q%3; v = w1[((size_t)c*TWO_D + d)*3 + i]; }
        else if (q < 350) { int r = q-150; int c = r/4, i = r%4; v = w2[((size_t)c*TWO_D + d)*4 + i]; }
        else              { int r = q-350; int c = r/5, i = r%5; v = w3[((size_t)c*TWO_D + d)*5 + i]; }
    }
    wtT[idx] = f2bf(v);
}

// ---------------- pa = emb@w1a + b1 ; pb = emb@w1b ----------------
__global__ void k_papb(const float* __restrict__ fv,
                       const float* __restrict__ w1a, const float* __restrict__ w1b,
                       const float* __restrict__ b1,
                       float* __restrict__ pa, float* __restrict__ pb) {
    int m = blockIdx.x;
    __shared__ float s_emb[D_];
    for (int d = threadIdx.x; d < D_; d += blockDim.x)
        s_emb[d] = fv[(size_t)m * TWO_D + d];
    __syncthreads();
    int h = threadIdx.x;   // 128 threads
    float acc_a = b1[h];
    float acc_b = 0.f;
    for (int d = 0; d < D_; ++d) {
        float e = s_emb[d];
        acc_a += e * w1a[(size_t)d * H_ + h];
        acc_b += e * w1b[(size_t)d * H_ + h];
    }
    pa[(size_t)m * H_ + h] = acc_a;
    pb[(size_t)m * H_ + h] = acc_b;
}

// ---------------- attention: one block per (b,i) ----------------
__global__ void k_attn(const float* __restrict__ pa, const float* __restrict__ pb,
                       const float* __restrict__ w2, const float* __restrict__ b2,
                       float* __restrict__ fv) {
    int m = blockIdx.x;
    int b = m >> 6, i = m & 63;
    __shared__ float s_pa[H_], s_w2[H_], s_sc[64];
    int tid = threadIdx.x;   // 256 threads = 4 waves
    if (tid < H_) { s_pa[tid] = pa[(size_t)m * H_ + tid]; s_w2[tid] = w2[tid]; }
    __syncthreads();
    int wave = tid >> 6, lane = tid & 63;
    float pa0 = s_pa[lane], pa1 = s_pa[lane + 64];
    float w20 = s_w2[lane], w21 = s_w2[lane + 64];
    float b2v = b2[0];
    for (int k = wave; k < L_ - 1; k += 4) {
        const float* pbr = pb + (size_t)(b * L_ + k) * H_;
        float p = w20 * tanhf(pa0 + pbr[lane]) + w21 * tanhf(pa1 + pbr[lane + 64]);
        #pragma unroll
        for (int off = 32; off; off >>= 1) p += __shfl_xor(p, off, 64);
        if (lane == 0) s_sc[k] = p + b2v;
    }
    __syncthreads();
    if (tid < 64) {
        float v = -INFINITY;
        if (tid < L_ - 1) {
            float e = fabsf((float)(i - tid)) - 1.0f;
            v = powf(0.9f, e) * s_sc[tid];
        }
        float mx = v;
        #pragma unroll
        for (int off = 32; off; off >>= 1) mx = fmaxf(mx, __shfl_xor(mx, off, 64));
        float ex = (tid < L_ - 1) ? expf(v - mx) : 0.f;
        float sm = ex;
        #pragma unroll
        for (int off = 32; off; off >>= 1) sm += __shfl_xor(sm, off, 64);
        if (tid < L_ - 1) s_sc[tid] = ex / sm;
    }
    __syncthreads();
    for (int d = tid; d < D_; d += blockDim.x) {
        float acc = 0.f;
        for (int k = 0; k < L_ - 1; ++k) {
            int j = k + (k >= i);
            acc += s_sc[k] * fv[(size_t)(b * L_ + j) * TWO_D + d];
        }
        fv[(size_t)m * TWO_D + D_ + d] = acc;
    }
}

// ---------------- convert fv (fp32 [4096][600]) -> fvb (bf16 [4096][608]) ----------------
__global__ void k_cvt(const float* __restrict__ fv, unsigned short* __restrict__ fvb) {
    int m = blockIdx.x;
    const float* src = fv + (size_t)m * TWO_D;
    unsigned short* dst = fvb + (size_t)m * KP;
    for (int d = threadIdx.x; d < KP; d += blockDim.x)
        dst[d] = (d < TWO_D) ? f2bf(src[d]) : 0;
}

// ---------------- MFMA GEMM: G[4096][600] = fvb[4096][608] @ WtT^T ----------------
// block: 256 thr (4 waves 2x2), tile 64x64, BK=32
#define PITCH 40   // LDS row pitch in bf16 (breaks bank-conflict stride)
__global__ __launch_bounds__(256) void k_gemm_mfma(const unsigned short* __restrict__ A,
                                                   const unsigned short* __restrict__ Bt,
                                                   float* __restrict__ G) {
    __shared__ unsigned short sA[64 * PITCH];
    __shared__ unsigned short sB[64 * PITCH];
    int m0 = blockIdx.x * 64;
    int q0 = blockIdx.y * 64;
    int tid = threadIdx.x;
    int lane = tid & 63, wave = tid >> 6;
    int wr = wave >> 1, wc = wave & 1;

    // staging indices: one 16B chunk per thread per tile
    int sr = tid >> 2;            // 0..63
    int so = (tid & 3) * 8;       // bf16 col offset 0/8/16/24

    floatx4 acc[2][2] = {};
    int lr = lane & 15;           // fragment row/col within 16
    int lk = (lane >> 4) * 8;     // k-slot base

    for (int k0 = 0; k0 < KP; k0 += 32) {
        uint4 va = *(const uint4*)&A [((size_t)(m0 + sr) * KP) + k0 + so];
        uint4 vb = *(const uint4*)&Bt[((size_t)(q0 + sr) * KP) + k0 + so];
        *(uint4*)&sA[sr * PITCH + so] = va;
        *(uint4*)&sB[sr * PITCH + so] = vb;
        __syncthreads();
        short8 a0 = *(const short8*)&sA[(wr * 32 +  0 + lr) * PITCH + lk];
        short8 a1 = *(const short8*)&sA[(wr * 32 + 16 + lr) * PITCH + lk];
        short8 b0 = *(const short8*)&sB[(wc * 32 +  0 + lr) * PITCH + lk];
        short8 b1 = *(const short8*)&sB[(wc * 32 + 16 + lr) * PITCH + lk];
        acc[0][0] = __builtin_amdgcn_mfma_f32_16x16x32_bf16(a0, b0, acc[0][0], 0, 0, 0);
        acc[0][1] = __builtin_amdgcn_mfma_f32_16x16x32_bf16(a0, b1, acc[0][1], 0, 0, 0);
        acc[1][0] = __builtin_amdgcn_mfma_f32_16x16x32_bf16(a1, b0, acc[1][0], 0, 0, 0);
        acc[1][1] = __builtin_amdgcn_mfma_f32_16x16x32_bf16(a1, b1, acc[1][1], 0, 0, 0);
        __syncthreads();
    }
    // epilogue: D lane mapping row=(lane>>4)*4+i, col=lane&15 (m89-verified)
    int drow = (lane >> 4) * 4;
    int dcol = lane & 15;
    #pragma unroll
    for (int mi = 0; mi < 2; ++mi) {
        #pragma unroll
        for (int ni = 0; ni < 2; ++ni) {
            int col = q0 + wc * 32 + ni * 16 + dcol;
            if (col >= Q_) continue;
            #pragma unroll
            for (int i = 0; i < 4; ++i) {
                int row = m0 + wr * 32 + mi * 16 + drow + i;
                G[(size_t)row * Q_ + col] = acc[mi][ni][i];
            }
        }
    }
}

// ---------------- conv bias + maxpool over valid t ----------------
__global__ void k_pool(const float* __restrict__ G, const float* __restrict__ cb1,
                       const float* __restrict__ cb2, const float* __restrict__ cb3,
                       float* __restrict__ conout) {
    int blk = blockIdx.x;
    int b = blk / 150, p = blk % 150;
    int ks, qb; float bias;
    if (p < 50)       { ks = 3; qb = p * 3;            bias = cb1[p]; }
    else if (p < 100) { int c = p - 50;  ks = 4; qb = 150 + c * 4; bias = cb2[c]; }
    else              { int c = p - 100; ks = 5; qb = 350 + c * 5; bias = cb3[c]; }
    int T = L_ - ks + 1;
    int t = threadIdx.x;
    float y = -INFINITY;
    if (t < T) {
        float s = bias;
        for (int i = 0; i < ks; ++i)
            s += G[(size_t)(b * L_ + t + i) * Q_ + qb + i];
        y = s;
    }
    #pragma unroll
    for (int off = 32; off; off >>= 1) y = fmaxf(y, __shfl_xor(y, off, 64));
    if (t == 0) conout[b * 150 + p] = y;
}

// ---------------- final linear + log_softmax ----------------
__global__ void k_final(const float* __restrict__ conout, const float* __restrict__ lw,
                        const float* __restrict__ lb, float* __restrict__ out) {
    int b = threadIdx.x;
    if (b >= B_) return;
    float l0 = lb[0], l1 = lb[1];
    const float* co = conout + b * 150;
    for (int m = 0; m < 150; ++m) {
        float v = co[m];
        l0 += v * lw[m * 2 + 0];
        l1 += v * lw[m * 2 + 1];
    }
    float mx = fmaxf(l0, l1);
    float ls = mx + logf(expf(l0 - mx) + expf(l1 - mx));
    out[b * 2 + 0] = l0 - ls;
    out[b * 2 + 1] = l1 - ls;
}

extern "C" void kernel_launch(void* const* d_in, const int* in_sizes, int n_in,
                              void* d_out, int out_size, void* d_ws, size_t ws_size,
                              hipStream_t stream) {
    const int*   x   = (const int*)  d_in[0];
    const float* em  = (const float*)d_in[1];
    const float* w1a = (const float*)d_in[2];
    const float* w1b = (const float*)d_in[3];
    const float* b1  = (const float*)d_in[4];
    const float* w2  = (const float*)d_in[5];
    const float* b2  = (const float*)d_in[6];
    const float* cw1 = (const float*)d_in[7];
    const float* cb1 = (const float*)d_in[8];
    const float* cw2 = (const float*)d_in[9];
    const float* cb2 = (const float*)d_in[10];
    const float* cw3 = (const float*)d_in[11];
    const float* cb3 = (const float*)d_in[12];
    const float* lw  = (const float*)d_in[13];
    const float* lb  = (const float*)d_in[14];
    float* out = (float*)d_out;

    float* ws = (float*)d_ws;
    float*          fv     = ws;                       // [4096][600] fp32; G aliases after cvt
    float*          G      = ws;                       // alias: fv dead after k_cvt
    float*          pa     = ws + 2457600;             // [4096][128]
    float*          pb     = ws + 2981888;             // [4096][128]
    unsigned short* fvb    = (unsigned short*)(ws + 3506176);  // [4096][608] bf16
    unsigned short* WtT    = (unsigned short*)(ws + 4751360);  // [640][608] bf16
    float*          conout = ws + 4945920;             // [64][150]
    // total ~19.8 MB

    hipLaunchKernelGGL(k_gather, dim3(M_), dim3(256), 0, stream, x, em, fv);
    hipLaunchKernelGGL(k_wtT, dim3((QP * KP + 255) / 256), dim3(256), 0, stream,
                       cw1, cw2, cw3, WtT);
    hipLaunchKernelGGL(k_papb, dim3(M_), dim3(128), 0, stream, fv, w1a, w1b, b1, pa, pb);
    hipLaunchKernelGGL(k_attn, dim3(M_), dim3(256), 0, stream, pa, pb, w2, b2, fv);
    hipLaunchKernelGGL(k_cvt, dim3(M_), dim3(256), 0, stream, fv, fvb);
    hipLaunchKernelGGL(k_gemm_mfma, dim3(M_ / 64, QP / 64), dim3(256), 0, stream,
                       fvb, WtT, G);
    hipLaunchKernelGGL(k_pool, dim3(B_ * 150), dim3(64), 0, stream, G, cb1, cb2, cb3, conout);
    hipLaunchKernelGGL(k_final, dim3(1), dim3(64), 0, stream, conout, lw, lb, out);
}

// Round 4
// 123.710 us; speedup vs baseline: 1.9908x; 1.3862x over previous
//
#include <hip/hip_runtime.h>
#include <math.h>

#define B_ 64
#define L_ 64
#define D_ 300
#define H_ 128
#define C_ 50
#define NC_ 2
#define TWO_D 600
#define M_ (B_*L_)      // 4096
#define Q_ 600          // logical conv columns
#define QP 640          // padded N for conv GEMM
#define KP 608          // fvb row stride (19*32)
#define KPA 320         // padded K for papb GEMM (10*32)
#define HH 256          // pa|pb concatenated width

typedef short short8 __attribute__((ext_vector_type(8)));
typedef float floatx4 __attribute__((ext_vector_type(4)));

static __device__ __forceinline__ unsigned short f2bf(float f) {
    unsigned int u = __float_as_uint(f);
    u += 0x7FFFu + ((u >> 16) & 1u);   // round-to-nearest-even
    return (unsigned short)(u >> 16);
}
static __device__ __forceinline__ float bf2f(unsigned short u) {
    return __uint_as_float(((unsigned int)u) << 16);
}
static __device__ __forceinline__ float fast_tanh(float x) {
    float e = __expf(2.0f * x);
    return 1.0f - 2.0f * __builtin_amdgcn_rcpf(e + 1.0f);
}

// ---------------- gather: fvb[m][0:300] = bf16(embedmatrix[x[m]]); pads zeroed ----------------
__global__ void k_gather(const int* __restrict__ x, const float* __restrict__ em,
                         unsigned short* __restrict__ fvb) {
    int m = blockIdx.x;
    int row = x[m];
    const float* src = em + (size_t)row * D_;
    unsigned short* dst = fvb + (size_t)m * KP;
    for (int d = threadIdx.x; d < KPA; d += blockDim.x)     // 0..319: emb + papb K-pad
        dst[d] = (d < D_) ? f2bf(src[d]) : 0;
    if (threadIdx.x < 8) dst[TWO_D + threadIdx.x] = 0;      // 600..607: conv K-pad
}

// ---------------- build WtT[q][d] (bf16 [640][608]) ----------------
__global__ void k_wtT(const float* __restrict__ w1, const float* __restrict__ w2,
                      const float* __restrict__ w3, unsigned short* __restrict__ wtT) {
    int idx = blockIdx.x * blockDim.x + threadIdx.x;
    if (idx >= QP * KP) return;
    int q = idx / KP, d = idx % KP;
    float v = 0.f;
    if (q < Q_ && d < TWO_D) {
        if (q < 150)      { int c = q/3,           i = q%3; v = w1[((size_t)c*TWO_D + d)*3 + i]; }
        else if (q < 350) { int r = q-150; int c = r/4, i = r%4; v = w2[((size_t)c*TWO_D + d)*4 + i]; }
        else              { int r = q-350; int c = r/5, i = r%5; v = w3[((size_t)c*TWO_D + d)*5 + i]; }
    }
    wtT[idx] = f2bf(v);
}

// ---------------- build w1abT[h][d] (bf16 [256][320]) from w1a|w1b ----------------
__global__ void k_w1abT(const float* __restrict__ w1a, const float* __restrict__ w1b,
                        unsigned short* __restrict__ wt) {
    int idx = blockIdx.x * blockDim.x + threadIdx.x;
    if (idx >= HH * KPA) return;
    int h = idx / KPA, d = idx % KPA;
    float v = 0.f;
    if (d < D_) v = (h < H_) ? w1a[(size_t)d * H_ + h] : w1b[(size_t)d * H_ + (h - H_)];
    wt[idx] = f2bf(v);
}

#define PITCH 40   // LDS row pitch in bf16

// ---------------- papb MFMA: pab[4096][256] = fvb[:,0:320] @ w1abT^T (+b1 on first 128) ----------------
__global__ __launch_bounds__(256) void k_papb_mfma(const unsigned short* __restrict__ A,
                                                   const unsigned short* __restrict__ Bt,
                                                   const float* __restrict__ b1,
                                                   float* __restrict__ pab) {
    __shared__ unsigned short sA[64 * PITCH];
    __shared__ unsigned short sB[64 * PITCH];
    int m0 = blockIdx.x * 64;
    int n0 = blockIdx.y * 64;
    int tid = threadIdx.x;
    int lane = tid & 63, wave = tid >> 6;
    int wr = wave >> 1, wc = wave & 1;
    int sr = tid >> 2, so = (tid & 3) * 8;
    floatx4 acc[2][2] = {};
    int lr = lane & 15, lk = (lane >> 4) * 8;
    for (int k0 = 0; k0 < KPA; k0 += 32) {
        uint4 va = *(const uint4*)&A [((size_t)(m0 + sr) * KP)  + k0 + so];
        uint4 vb = *(const uint4*)&Bt[((size_t)(n0 + sr) * KPA) + k0 + so];
        *(uint4*)&sA[sr * PITCH + so] = va;
        *(uint4*)&sB[sr * PITCH + so] = vb;
        __syncthreads();
        short8 a0 = *(const short8*)&sA[(wr * 32 +  0 + lr) * PITCH + lk];
        short8 a1 = *(const short8*)&sA[(wr * 32 + 16 + lr) * PITCH + lk];
        short8 b0 = *(const short8*)&sB[(wc * 32 +  0 + lr) * PITCH + lk];
        short8 b1f= *(const short8*)&sB[(wc * 32 + 16 + lr) * PITCH + lk];
        acc[0][0] = __builtin_amdgcn_mfma_f32_16x16x32_bf16(a0, b0, acc[0][0], 0, 0, 0);
        acc[0][1] = __builtin_amdgcn_mfma_f32_16x16x32_bf16(a0, b1f, acc[0][1], 0, 0, 0);
        acc[1][0] = __builtin_amdgcn_mfma_f32_16x16x32_bf16(a1, b0, acc[1][0], 0, 0, 0);
        acc[1][1] = __builtin_amdgcn_mfma_f32_16x16x32_bf16(a1, b1f, acc[1][1], 0, 0, 0);
        __syncthreads();
    }
    int drow = (lane >> 4) * 4, dcol = lane & 15;
    #pragma unroll
    for (int mi = 0; mi < 2; ++mi)
        #pragma unroll
        for (int ni = 0; ni < 2; ++ni) {
            int col = n0 + wc * 32 + ni * 16 + dcol;
            float bias = (col < H_) ? b1[col] : 0.f;
            #pragma unroll
            for (int i = 0; i < 4; ++i) {
                int row = m0 + wr * 32 + mi * 16 + drow + i;
                pab[(size_t)row * HH + col] = acc[mi][ni][i] + bias;
            }
        }
}

// ---------------- attention: one block per (b,i) ----------------
__global__ void k_attn(const float* __restrict__ pab,
                       const float* __restrict__ w2, const float* __restrict__ b2,
                       unsigned short* __restrict__ fvb) {
    int m = blockIdx.x;
    int b = m >> 6, i = m & 63;
    __shared__ float s_pa[H_], s_w2[H_], s_sc[64];
    int tid = threadIdx.x;   // 256 threads = 4 waves
    if (tid < H_) { s_pa[tid] = pab[(size_t)m * HH + tid]; s_w2[tid] = w2[tid]; }
    __syncthreads();
    int wave = tid >> 6, lane = tid & 63;
    float pa0 = s_pa[lane], pa1 = s_pa[lane + 64];
    float w20 = s_w2[lane], w21 = s_w2[lane + 64];
    float b2v = b2[0];
    for (int k = wave; k < L_ - 1; k += 4) {
        const float* pbr = pab + (size_t)(b * L_ + k) * HH + H_;
        float p = w20 * fast_tanh(pa0 + pbr[lane]) + w21 * fast_tanh(pa1 + pbr[lane + 64]);
        #pragma unroll
        for (int off = 32; off; off >>= 1) p += __shfl_xor(p, off, 64);
        if (lane == 0) s_sc[k] = p + b2v;
    }
    __syncthreads();
    if (tid < 64) {
        float v = -INFINITY;
        if (tid < L_ - 1) {
            float e = fabsf((float)(i - tid)) - 1.0f;
            v = __expf(e * -0.10536051565782628f) * s_sc[tid];   // 0.9^e
        }
        float mx = v;
        #pragma unroll
        for (int off = 32; off; off >>= 1) mx = fmaxf(mx, __shfl_xor(mx, off, 64));
        float ex = (tid < L_ - 1) ? __expf(v - mx) : 0.f;
        float sm = ex;
        #pragma unroll
        for (int off = 32; off; off >>= 1) sm += __shfl_xor(sm, off, 64);
        if (tid < L_ - 1) s_sc[tid] = ex * __builtin_amdgcn_rcpf(sm);
    }
    __syncthreads();
    // att[b,i,d] = sum_k alpha[k] * emb[b, j, d],  j = k + (k>=i); write bf16 into fvb cols 300:600
    for (int d = tid; d < D_; d += blockDim.x) {
        float acc = 0.f;
        for (int k = 0; k < L_ - 1; ++k) {
            int j = k + (k >= i);
            acc += s_sc[k] * bf2f(fvb[(size_t)(b * L_ + j) * KP + d]);
        }
        fvb[(size_t)m * KP + D_ + d] = f2bf(acc);
    }
}

// ---------------- conv MFMA GEMM: G[4096][600] = fvb[4096][608] @ WtT^T ----------------
__global__ __launch_bounds__(256) void k_gemm_mfma(const unsigned short* __restrict__ A,
                                                   const unsigned short* __restrict__ Bt,
                                                   float* __restrict__ G) {
    __shared__ unsigned short sA[64 * PITCH];
    __shared__ unsigned short sB[64 * PITCH];
    int m0 = blockIdx.x * 64;
    int q0 = blockIdx.y * 64;
    int tid = threadIdx.x;
    int lane = tid & 63, wave = tid >> 6;
    int wr = wave >> 1, wc = wave & 1;
    int sr = tid >> 2, so = (tid & 3) * 8;
    floatx4 acc[2][2] = {};
    int lr = lane & 15, lk = (lane >> 4) * 8;
    for (int k0 = 0; k0 < KP; k0 += 32) {
        uint4 va = *(const uint4*)&A [((size_t)(m0 + sr) * KP) + k0 + so];
        uint4 vb = *(const uint4*)&Bt[((size_t)(q0 + sr) * KP) + k0 + so];
        *(uint4*)&sA[sr * PITCH + so] = va;
        *(uint4*)&sB[sr * PITCH + so] = vb;
        __syncthreads();
        short8 a0 = *(const short8*)&sA[(wr * 32 +  0 + lr) * PITCH + lk];
        short8 a1 = *(const short8*)&sA[(wr * 32 + 16 + lr) * PITCH + lk];
        short8 b0 = *(const short8*)&sB[(wc * 32 +  0 + lr) * PITCH + lk];
        short8 b1 = *(const short8*)&sB[(wc * 32 + 16 + lr) * PITCH + lk];
        acc[0][0] = __builtin_amdgcn_mfma_f32_16x16x32_bf16(a0, b0, acc[0][0], 0, 0, 0);
        acc[0][1] = __builtin_amdgcn_mfma_f32_16x16x32_bf16(a0, b1, acc[0][1], 0, 0, 0);
        acc[1][0] = __builtin_amdgcn_mfma_f32_16x16x32_bf16(a1, b0, acc[1][0], 0, 0, 0);
        acc[1][1] = __builtin_amdgcn_mfma_f32_16x16x32_bf16(a1, b1, acc[1][1], 0, 0, 0);
        __syncthreads();
    }
    int drow = (lane >> 4) * 4, dcol = lane & 15;
    #pragma unroll
    for (int mi = 0; mi < 2; ++mi)
        #pragma unroll
        for (int ni = 0; ni < 2; ++ni) {
            int col = q0 + wc * 32 + ni * 16 + dcol;
            if (col >= Q_) continue;
            #pragma unroll
            for (int i = 0; i < 4; ++i) {
                int row = m0 + wr * 32 + mi * 16 + drow + i;
                G[(size_t)row * Q_ + col] = acc[mi][ni][i];
            }
        }
}

// ---------------- conv bias + maxpool over valid t ----------------
__global__ void k_pool(const float* __restrict__ G, const float* __restrict__ cb1,
                       const float* __restrict__ cb2, const float* __restrict__ cb3,
                       float* __restrict__ conout) {
    int blk = blockIdx.x;
    int b = blk / 150, p = blk % 150;
    int ks, qb; float bias;
    if (p < 50)       { ks = 3; qb = p * 3;            bias = cb1[p]; }
    else if (p < 100) { int c = p - 50;  ks = 4; qb = 150 + c * 4; bias = cb2[c]; }
    else              { int c = p - 100; ks = 5; qb = 350 + c * 5; bias = cb3[c]; }
    int T = L_ - ks + 1;
    int t = threadIdx.x;
    float y = -INFINITY;
    if (t < T) {
        float s = bias;
        for (int i = 0; i < ks; ++i)
            s += G[(size_t)(b * L_ + t + i) * Q_ + qb + i];
        y = s;
    }
    #pragma unroll
    for (int off = 32; off; off >>= 1) y = fmaxf(y, __shfl_xor(y, off, 64));
    if (t == 0) conout[b * 150 + p] = y;
}

// ---------------- final linear + log_softmax ----------------
__global__ void k_final(const float* __restrict__ conout, const float* __restrict__ lw,
                        const float* __restrict__ lb, float* __restrict__ out) {
    int b = threadIdx.x;
    if (b >= B_) return;
    float l0 = lb[0], l1 = lb[1];
    const float* co = conout + b * 150;
    for (int m = 0; m < 150; ++m) {
        float v = co[m];
        l0 += v * lw[m * 2 + 0];
        l1 += v * lw[m * 2 + 1];
    }
    float mx = fmaxf(l0, l1);
    float ls = mx + logf(expf(l0 - mx) + expf(l1 - mx));
    out[b * 2 + 0] = l0 - ls;
    out[b * 2 + 1] = l1 - ls;
}

extern "C" void kernel_launch(void* const* d_in, const int* in_sizes, int n_in,
                              void* d_out, int out_size, void* d_ws, size_t ws_size,
                              hipStream_t stream) {
    const int*   x   = (const int*)  d_in[0];
    const float* em  = (const float*)d_in[1];
    const float* w1a = (const float*)d_in[2];
    const float* w1b = (const float*)d_in[3];
    const float* b1  = (const float*)d_in[4];
    const float* w2  = (const float*)d_in[5];
    const float* b2  = (const float*)d_in[6];
    const float* cw1 = (const float*)d_in[7];
    const float* cb1 = (const float*)d_in[8];
    const float* cw2 = (const float*)d_in[9];
    const float* cb2 = (const float*)d_in[10];
    const float* cw3 = (const float*)d_in[11];
    const float* cb3 = (const float*)d_in[12];
    const float* lw  = (const float*)d_in[13];
    const float* lb  = (const float*)d_in[14];
    float* out = (float*)d_out;

    float* ws = (float*)d_ws;
    float*          G      = ws;                                 // [4096][600] f32
    float*          pab    = ws + 2457600;                       // [4096][256] f32
    unsigned short* fvb    = (unsigned short*)(ws + 3506176);    // [4096][608] bf16
    unsigned short* WtT    = (unsigned short*)(ws + 4751360);    // [640][608]  bf16
    unsigned short* w1abT  = (unsigned short*)(ws + 4945920);    // [256][320]  bf16
    float*          conout = ws + 4986880;                       // [64][150]   f32
    // total ~20.0 MB

    hipLaunchKernelGGL(k_gather, dim3(M_), dim3(256), 0, stream, x, em, fvb);
    hipLaunchKernelGGL(k_wtT, dim3((QP * KP + 255) / 256), dim3(256), 0, stream,
                       cw1, cw2, cw3, WtT);
    hipLaunchKernelGGL(k_w1abT, dim3((HH * KPA + 255) / 256), dim3(256), 0, stream,
                       w1a, w1b, w1abT);
    hipLaunchKernelGGL(k_papb_mfma, dim3(M_ / 64, HH / 64), dim3(256), 0, stream,
                       fvb, w1abT, b1, pab);
    hipLaunchKernelGGL(k_attn, dim3(M_), dim3(256), 0, stream, pab, w2, b2, fvb);
    hipLaunchKernelGGL(k_gemm_mfma, dim3(M_ / 64, QP / 64), dim3(256), 0, stream,
                       fvb, WtT, G);
    hipLaunchKernelGGL(k_pool, dim3(B_ * 150), dim3(64), 0, stream, G, cb1, cb2, cb3, conout);
    hipLaunchKernelGGL(k_final, dim3(1), dim3(64), 0, stream, conout, lw, lb, out);
}

// Round 5
// 89.108 us; speedup vs baseline: 2.7639x; 1.3883x over previous
//
#include <hip/hip_runtime.h>
#include <math.h>

#define B_ 64
#define L_ 64
#define D_ 300
#define H_ 128
#define C_ 50
#define NC_ 2
#define TWO_D 600
#define M_ (B_*L_)      // 4096
#define Q_ 600          // logical conv columns
#define QP 640          // padded N for conv GEMM
#define KP 608          // fvb row stride (19*32)
#define KPA 320         // padded K for papb GEMM (10*32)
#define HH 256          // pa|pb concatenated width

typedef short short8 __attribute__((ext_vector_type(8)));
typedef float floatx4 __attribute__((ext_vector_type(4)));

static __device__ __forceinline__ unsigned short f2bf(float f) {
    unsigned int u = __float_as_uint(f);
    u += 0x7FFFu + ((u >> 16) & 1u);   // round-to-nearest-even
    return (unsigned short)(u >> 16);
}
static __device__ __forceinline__ float bf2f(unsigned short u) {
    return __uint_as_float(((unsigned int)u) << 16);
}
static __device__ __forceinline__ float fast_tanh(float x) {
    float e = __expf(2.0f * x);
    return 1.0f - 2.0f * __builtin_amdgcn_rcpf(e + 1.0f);
}

// ---------------- gather: fvb[m][0:300] = bf16(embedmatrix[x[m]]); pads zeroed ----------------
__global__ void k_gather(const int* __restrict__ x, const float* __restrict__ em,
                         unsigned short* __restrict__ fvb) {
    int m = blockIdx.x;
    int row = x[m];
    const float* src = em + (size_t)row * D_;
    unsigned short* dst = fvb + (size_t)m * KP;
    for (int d = threadIdx.x; d < KPA; d += blockDim.x)     // 0..319: emb + papb K-pad
        dst[d] = (d < D_) ? f2bf(src[d]) : 0;
    if (threadIdx.x < 8) dst[TWO_D + threadIdx.x] = 0;      // 600..607: conv K-pad
}

// ---------------- build WtT[q][d] (bf16 [640][608]) ----------------
__global__ void k_wtT(const float* __restrict__ w1, const float* __restrict__ w2,
                      const float* __restrict__ w3, unsigned short* __restrict__ wtT) {
    int idx = blockIdx.x * blockDim.x + threadIdx.x;
    if (idx >= QP * KP) return;
    int q = idx / KP, d = idx % KP;
    float v = 0.f;
    if (q < Q_ && d < TWO_D) {
        if (q < 150)      { int c = q/3,           i = q%3; v = w1[((size_t)c*TWO_D + d)*3 + i]; }
        else if (q < 350) { int r = q-150; int c = r/4, i = r%4; v = w2[((size_t)c*TWO_D + d)*4 + i]; }
        else              { int r = q-350; int c = r/5, i = r%5; v = w3[((size_t)c*TWO_D + d)*5 + i]; }
    }
    wtT[idx] = f2bf(v);
}

// ---------------- build w1abT[h][d] (bf16 [256][320]) from w1a|w1b ----------------
__global__ void k_w1abT(const float* __restrict__ w1a, const float* __restrict__ w1b,
                        unsigned short* __restrict__ wt) {
    int idx = blockIdx.x * blockDim.x + threadIdx.x;
    if (idx >= HH * KPA) return;
    int h = idx / KPA, d = idx % KPA;
    float v = 0.f;
    if (d < D_) v = (h < H_) ? w1a[(size_t)d * H_ + h] : w1b[(size_t)d * H_ + (h - H_)];
    wt[idx] = f2bf(v);
}

#define PITCH 40   // LDS row pitch in bf16

// ---------------- papb MFMA: pab[4096][256] = fvb[:,0:320] @ w1abT^T (+b1 on first 128) ----------------
__global__ __launch_bounds__(256) void k_papb_mfma(const unsigned short* __restrict__ A,
                                                   const unsigned short* __restrict__ Bt,
                                                   const float* __restrict__ b1,
                                                   float* __restrict__ pab) {
    __shared__ unsigned short sA[64 * PITCH];
    __shared__ unsigned short sB[64 * PITCH];
    int m0 = blockIdx.x * 64;
    int n0 = blockIdx.y * 64;
    int tid = threadIdx.x;
    int lane = tid & 63, wave = tid >> 6;
    int wr = wave >> 1, wc = wave & 1;
    int sr = tid >> 2, so = (tid & 3) * 8;
    floatx4 acc[2][2] = {};
    int lr = lane & 15, lk = (lane >> 4) * 8;
    for (int k0 = 0; k0 < KPA; k0 += 32) {
        uint4 va = *(const uint4*)&A [((size_t)(m0 + sr) * KP)  + k0 + so];
        uint4 vb = *(const uint4*)&Bt[((size_t)(n0 + sr) * KPA) + k0 + so];
        *(uint4*)&sA[sr * PITCH + so] = va;
        *(uint4*)&sB[sr * PITCH + so] = vb;
        __syncthreads();
        short8 a0 = *(const short8*)&sA[(wr * 32 +  0 + lr) * PITCH + lk];
        short8 a1 = *(const short8*)&sA[(wr * 32 + 16 + lr) * PITCH + lk];
        short8 b0 = *(const short8*)&sB[(wc * 32 +  0 + lr) * PITCH + lk];
        short8 b1f= *(const short8*)&sB[(wc * 32 + 16 + lr) * PITCH + lk];
        acc[0][0] = __builtin_amdgcn_mfma_f32_16x16x32_bf16(a0, b0, acc[0][0], 0, 0, 0);
        acc[0][1] = __builtin_amdgcn_mfma_f32_16x16x32_bf16(a0, b1f, acc[0][1], 0, 0, 0);
        acc[1][0] = __builtin_amdgcn_mfma_f32_16x16x32_bf16(a1, b0, acc[1][0], 0, 0, 0);
        acc[1][1] = __builtin_amdgcn_mfma_f32_16x16x32_bf16(a1, b1f, acc[1][1], 0, 0, 0);
        __syncthreads();
    }
    int drow = (lane >> 4) * 4, dcol = lane & 15;
    #pragma unroll
    for (int mi = 0; mi < 2; ++mi)
        #pragma unroll
        for (int ni = 0; ni < 2; ++ni) {
            int col = n0 + wc * 32 + ni * 16 + dcol;
            float bias = (col < H_) ? b1[col] : 0.f;
            #pragma unroll
            for (int i = 0; i < 4; ++i) {
                int row = m0 + wr * 32 + mi * 16 + drow + i;
                pab[(size_t)row * HH + col] = acc[mi][ni][i] + bias;
            }
        }
}

// ---------------- attention scores+softmax: lane-owns-k, wave-owns-i ----------------
// 1024 blocks: blk = b*16 + i0/4. Writes alpha_full rows (bf16) into af[4096][64].
#define AT_PITCH 132
__global__ __launch_bounds__(256) void k_attn(const float* __restrict__ pab,
                                              const float* __restrict__ w2g,
                                              const float* __restrict__ b2,
                                              unsigned short* __restrict__ af) {
    int blk = blockIdx.x;
    int b = blk >> 4;
    int i0 = (blk & 15) * 4;
    __shared__ float pbL[64 * AT_PITCH];
    __shared__ float paL[4 * 128];
    __shared__ float s_w2[128];
    int tid = threadIdx.x, wave = tid >> 6, lane = tid & 63;

    // stage pb block: rows k=0..63, cols h=0..127  (pab cols 128..255)
    int r = tid >> 2, c0 = (tid & 3) * 32;
    #pragma unroll
    for (int c = 0; c < 32; c += 4) {
        float4 v = *(const float4*)&pab[(size_t)(b * 64 + r) * HH + 128 + c0 + c];
        *(float4*)&pbL[r * AT_PITCH + c0 + c] = v;
    }
    if (tid < 128) s_w2[tid] = w2g[tid];
    for (int e = tid; e < 512; e += 256) {
        int ri = e >> 7, h = e & 127;
        paL[e] = pab[(size_t)(b * 64 + i0 + ri) * HH + h];
    }
    __syncthreads();

    int i = i0 + wave;
    int k = lane;
    float p = 0.f;
    for (int h = 0; h < 128; h += 4) {
        float4 pb4 = *(const float4*)&pbL[k * AT_PITCH + h];
        float4 pa4 = *(const float4*)&paL[wave * 128 + h];
        float4 w4  = *(const float4*)&s_w2[h];
        p += w4.x * fast_tanh(pa4.x + pb4.x);
        p += w4.y * fast_tanh(pa4.y + pb4.y);
        p += w4.z * fast_tanh(pa4.z + pb4.z);
        p += w4.w * fast_tanh(pa4.w + pb4.w);
    }
    p += b2[0];
    float v;
    if (k < 63) {
        float e = fabsf((float)(i - k)) - 1.0f;     // compacted index for decay
        v = __expf(e * -0.10536051565782628f) * p;  // 0.9^e * s
    } else v = -INFINITY;
    float mx = v;
    #pragma unroll
    for (int off = 32; off; off >>= 1) mx = fmaxf(mx, __shfl_xor(mx, off, 64));
    float ex = (k < 63) ? __expf(v - mx) : 0.f;
    float sm = ex;
    #pragma unroll
    for (int off = 32; off; off >>= 1) sm += __shfl_xor(sm, off, 64);
    float alpha = ex * __builtin_amdgcn_rcpf(sm);
    int j = (k < 63) ? (k + (k >= i)) : i;          // lane 63 zeroes the diagonal
    af[(size_t)(b * 64 + i) * 64 + j] = (k < 63) ? f2bf(alpha) : (unsigned short)0;
}

// ---------------- att = alpha_full @ emb, per-b batched MFMA; writes fvb[:,300:600] ----------------
__global__ __launch_bounds__(256) void k_att_mfma(const unsigned short* __restrict__ af,
                                                  unsigned short* __restrict__ fvb) {
    int b = blockIdx.x;            // 0..63
    int n0 = blockIdx.y * 64;      // d-tile base: 0..256
    __shared__ unsigned short sA[64 * 72];   // alpha_full rows [i][m]
    __shared__ unsigned short sBt[64 * 72];  // E^T [dd][m]
    int tid = threadIdx.x, wave = tid >> 6, lane = tid & 63;

    int sr = tid >> 2, so = (tid & 3) * 16;
    *(uint4*)&sA[sr * 72 + so]     = *(const uint4*)&af[(size_t)(b * 64 + sr) * 64 + so];
    *(uint4*)&sA[sr * 72 + so + 8] = *(const uint4*)&af[(size_t)(b * 64 + sr) * 64 + so + 8];

    int dg = n0 + lane;
    #pragma unroll
    for (int p = 0; p < 16; ++p) {
        int m = p * 4 + wave;
        unsigned short v = (dg < D_) ? fvb[(size_t)(b * 64 + m) * KP + dg] : (unsigned short)0;
        sBt[lane * 72 + m] = v;    // transpose scatter (8-way write conflict, tiny volume)
    }
    __syncthreads();

    int wr = wave >> 1, wc = wave & 1;
    int lr = lane & 15, lk = (lane >> 4) * 8;
    floatx4 acc[2][2] = {};
    #pragma unroll
    for (int k0 = 0; k0 < 64; k0 += 32) {
        short8 a0 = *(const short8*)&sA [(wr * 32 +  0 + lr) * 72 + k0 + lk];
        short8 a1 = *(const short8*)&sA [(wr * 32 + 16 + lr) * 72 + k0 + lk];
        short8 b0 = *(const short8*)&sBt[(wc * 32 +  0 + lr) * 72 + k0 + lk];
        short8 b1 = *(const short8*)&sBt[(wc * 32 + 16 + lr) * 72 + k0 + lk];
        acc[0][0] = __builtin_amdgcn_mfma_f32_16x16x32_bf16(a0, b0, acc[0][0], 0, 0, 0);
        acc[0][1] = __builtin_amdgcn_mfma_f32_16x16x32_bf16(a0, b1, acc[0][1], 0, 0, 0);
        acc[1][0] = __builtin_amdgcn_mfma_f32_16x16x32_bf16(a1, b0, acc[1][0], 0, 0, 0);
        acc[1][1] = __builtin_amdgcn_mfma_f32_16x16x32_bf16(a1, b1, acc[1][1], 0, 0, 0);
    }
    int drow = (lane >> 4) * 4, dcol = lane & 15;
    #pragma unroll
    for (int mi = 0; mi < 2; ++mi)
        #pragma unroll
        for (int ni = 0; ni < 2; ++ni) {
            int col = wc * 32 + ni * 16 + dcol;
            int dgo = n0 + col;
            if (dgo >= D_) continue;
            #pragma unroll
            for (int i = 0; i < 4; ++i) {
                int row = wr * 32 + mi * 16 + drow + i;
                fvb[(size_t)(b * 64 + row) * KP + D_ + dgo] = f2bf(acc[mi][ni][i]);
            }
        }
}

// ---------------- conv MFMA GEMM: G[4096][600] = fvb[4096][608] @ WtT^T ----------------
__global__ __launch_bounds__(256) void k_gemm_mfma(const unsigned short* __restrict__ A,
                                                   const unsigned short* __restrict__ Bt,
                                                   float* __restrict__ G) {
    __shared__ unsigned short sA[64 * PITCH];
    __shared__ unsigned short sB[64 * PITCH];
    int m0 = blockIdx.x * 64;
    int q0 = blockIdx.y * 64;
    int tid = threadIdx.x;
    int lane = tid & 63, wave = tid >> 6;
    int wr = wave >> 1, wc = wave & 1;
    int sr = tid >> 2, so = (tid & 3) * 8;
    floatx4 acc[2][2] = {};
    int lr = lane & 15, lk = (lane >> 4) * 8;
    for (int k0 = 0; k0 < KP; k0 += 32) {
        uint4 va = *(const uint4*)&A [((size_t)(m0 + sr) * KP) + k0 + so];
        uint4 vb = *(const uint4*)&Bt[((size_t)(q0 + sr) * KP) + k0 + so];
        *(uint4*)&sA[sr * PITCH + so] = va;
        *(uint4*)&sB[sr * PITCH + so] = vb;
        __syncthreads();
        short8 a0 = *(const short8*)&sA[(wr * 32 +  0 + lr) * PITCH + lk];
        short8 a1 = *(const short8*)&sA[(wr * 32 + 16 + lr) * PITCH + lk];
        short8 b0 = *(const short8*)&sB[(wc * 32 +  0 + lr) * PITCH + lk];
        short8 b1 = *(const short8*)&sB[(wc * 32 + 16 + lr) * PITCH + lk];
        acc[0][0] = __builtin_amdgcn_mfma_f32_16x16x32_bf16(a0, b0, acc[0][0], 0, 0, 0);
        acc[0][1] = __builtin_amdgcn_mfma_f32_16x16x32_bf16(a0, b1, acc[0][1], 0, 0, 0);
        acc[1][0] = __builtin_amdgcn_mfma_f32_16x16x32_bf16(a1, b0, acc[1][0], 0, 0, 0);
        acc[1][1] = __builtin_amdgcn_mfma_f32_16x16x32_bf16(a1, b1, acc[1][1], 0, 0, 0);
        __syncthreads();
    }
    int drow = (lane >> 4) * 4, dcol = lane & 15;
    #pragma unroll
    for (int mi = 0; mi < 2; ++mi)
        #pragma unroll
        for (int ni = 0; ni < 2; ++ni) {
            int col = q0 + wc * 32 + ni * 16 + dcol;
            if (col >= Q_) continue;
            #pragma unroll
            for (int i = 0; i < 4; ++i) {
                int row = m0 + wr * 32 + mi * 16 + drow + i;
                G[(size_t)row * Q_ + col] = acc[mi][ni][i];
            }
        }
}

// ---------------- conv bias + maxpool over valid t ----------------
__global__ void k_pool(const float* __restrict__ G, const float* __restrict__ cb1,
                       const float* __restrict__ cb2, const float* __restrict__ cb3,
                       float* __restrict__ conout) {
    int blk = blockIdx.x;
    int b = blk / 150, p = blk % 150;
    int ks, qb; float bias;
    if (p < 50)       { ks = 3; qb = p * 3;            bias = cb1[p]; }
    else if (p < 100) { int c = p - 50;  ks = 4; qb = 150 + c * 4; bias = cb2[c]; }
    else              { int c = p - 100; ks = 5; qb = 350 + c * 5; bias = cb3[c]; }
    int T = L_ - ks + 1;
    int t = threadIdx.x;
    float y = -INFINITY;
    if (t < T) {
        float s = bias;
        for (int i = 0; i < ks; ++i)
            s += G[(size_t)(b * L_ + t + i) * Q_ + qb + i];
        y = s;
    }
    #pragma unroll
    for (int off = 32; off; off >>= 1) y = fmaxf(y, __shfl_xor(y, off, 64));
    if (t == 0) conout[b * 150 + p] = y;
}

// ---------------- final linear + log_softmax ----------------
__global__ void k_final(const float* __restrict__ conout, const float* __restrict__ lw,
                        const float* __restrict__ lb, float* __restrict__ out) {
    int b = threadIdx.x;
    if (b >= B_) return;
    float l0 = lb[0], l1 = lb[1];
    const float* co = conout + b * 150;
    for (int m = 0; m < 150; ++m) {
        float v = co[m];
        l0 += v * lw[m * 2 + 0];
        l1 += v * lw[m * 2 + 1];
    }
    float mx = fmaxf(l0, l1);
    float ls = mx + logf(expf(l0 - mx) + expf(l1 - mx));
    out[b * 2 + 0] = l0 - ls;
    out[b * 2 + 1] = l1 - ls;
}

extern "C" void kernel_launch(void* const* d_in, const int* in_sizes, int n_in,
                              void* d_out, int out_size, void* d_ws, size_t ws_size,
                              hipStream_t stream) {
    const int*   x   = (const int*)  d_in[0];
    const float* em  = (const float*)d_in[1];
    const float* w1a = (const float*)d_in[2];
    const float* w1b = (const float*)d_in[3];
    const float* b1  = (const float*)d_in[4];
    const float* w2  = (const float*)d_in[5];
    const float* b2  = (const float*)d_in[6];
    const float* cw1 = (const float*)d_in[7];
    const float* cb1 = (const float*)d_in[8];
    const float* cw2 = (const float*)d_in[9];
    const float* cb2 = (const float*)d_in[10];
    const float* cw3 = (const float*)d_in[11];
    const float* cb3 = (const float*)d_in[12];
    const float* lw  = (const float*)d_in[13];
    const float* lb  = (const float*)d_in[14];
    float* out = (float*)d_out;

    float* ws = (float*)d_ws;
    float*          G      = ws;                                 // [4096][600] f32
    unsigned short* af     = (unsigned short*)ws;                // [4096][64] bf16 — dead before G is written
    float*          pab    = ws + 2457600;                       // [4096][256] f32
    unsigned short* fvb    = (unsigned short*)(ws + 3506176);    // [4096][608] bf16
    unsigned short* WtT    = (unsigned short*)(ws + 4751360);    // [640][608]  bf16
    unsigned short* w1abT  = (unsigned short*)(ws + 4945920);    // [256][320]  bf16
    float*          conout = ws + 4986880;                       // [64][150]   f32
    // total ~20.0 MB

    hipLaunchKernelGGL(k_gather, dim3(M_), dim3(256), 0, stream, x, em, fvb);
    hipLaunchKernelGGL(k_wtT, dim3((QP * KP + 255) / 256), dim3(256), 0, stream,
                       cw1, cw2, cw3, WtT);
    hipLaunchKernelGGL(k_w1abT, dim3((HH * KPA + 255) / 256), dim3(256), 0, stream,
                       w1a, w1b, w1abT);
    hipLaunchKernelGGL(k_papb_mfma, dim3(M_ / 64, HH / 64), dim3(256), 0, stream,
                       fvb, w1abT, b1, pab);
    hipLaunchKernelGGL(k_attn, dim3(1024), dim3(256), 0, stream, pab, w2, b2, af);
    hipLaunchKernelGGL(k_att_mfma, dim3(B_, 5), dim3(256), 0, stream, af, fvb);
    hipLaunchKernelGGL(k_gemm_mfma, dim3(M_ / 64, QP / 64), dim3(256), 0, stream,
                       fvb, WtT, G);
    hipLaunchKernelGGL(k_pool, dim3(B_ * 150), dim3(64), 0, stream, G, cb1, cb2, cb3, conout);
    hipLaunchKernelGGL(k_final, dim3(1), dim3(64), 0, stream, conout, lw, lb, out);
}